// Round 13
// baseline (407.421 us; speedup 1.0000x reference)
//
#include <hip/hip_runtime.h>
#include <hip/hip_bf16.h>
#include <stdint.h>

// Problem dims (fixed by harness)
#define Bb 256
#define Nn 196
#define Dd 384
#define Hh 1536
#define NPAD 224      // patch-dim K padded to 7*32 for MFMA
#define MPAD 256      // Wq row pad to 2*128 tiles
#define TTOT (Bb*Nn)  // 50176 tokens
#define XLD 232       // padded LDS stride for Xs (224+8): breaks bank aliasing
#define TC 25088      // tokens per MLP chunk (2 chunks; h2 live set 77 MB -> partial L3)

typedef __attribute__((ext_vector_type(8))) __bf16 bf16x8;
typedef __attribute__((ext_vector_type(4))) float f32x4;

// async global->LDS, 16B per lane. LDS dest must be wave-uniform base + lane*16.
#define GLD16(gp, lp) __builtin_amdgcn_global_load_lds( \
    (const __attribute__((address_space(1))) void*)(gp), \
    (__attribute__((address_space(3))) void*)(lp), 16, 0, 0)

#define MFMA16(a, b, c) __builtin_amdgcn_mfma_f32_16x16x32_bf16((a), (b), (c), 0, 0, 0)

__device__ __forceinline__ ushort f2bf(float f){
  union { float f; unsigned u; } v; v.f = f;
  unsigned r = v.u + 0x7FFFu + ((v.u >> 16) & 1u);   // RNE f32->bf16
  return (ushort)(r >> 16);
}

// ---------- absmax over the three weight tensors in one launch (y = tensor id) ----------
__global__ void absmax3_k(const float* __restrict__ wa, const float* __restrict__ w1,
                          const float* __restrict__ w2, unsigned* __restrict__ out){
  int which = blockIdx.y;
  const float* w = which == 0 ? wa : (which == 1 ? w1 : w2);
  int n = which == 0 ? Nn*Nn : Hh*Dd;
  float m = 0.f;
  for (int i = blockIdx.x*blockDim.x + threadIdx.x; i < n; i += gridDim.x*blockDim.x)
    m = fmaxf(m, fabsf(w[i]));
  #pragma unroll
  for (int o = 32; o >= 1; o >>= 1) m = fmaxf(m, __shfl_xor(m, o));
  __shared__ float sm[4];
  if ((threadIdx.x & 63) == 0) sm[threadIdx.x >> 6] = m;
  __syncthreads();
  if (threadIdx.x == 0){
    float mm = fmaxf(fmaxf(sm[0], sm[1]), fmaxf(sm[2], sm[3]));
    atomicMax(out + which, __float_as_uint(mm));   // floats >=0: uint order == float order
  }
}

// ---------- fake-quant all three weights in one launch (y = tensor id) ----------
__global__ void quant_all_k(const float* __restrict__ Wa, const float* __restrict__ W1,
                            const float* __restrict__ W2, const unsigned* __restrict__ amax,
                            const int* __restrict__ bitsp,
                            ushort* __restrict__ Wq, ushort* __restrict__ W1q,
                            ushort* __restrict__ W2q){
  const int which = blockIdx.y;
  const int idx = blockIdx.x*256 + threadIdx.x;
  const float qmax = (float)((1 << (bitsp[0]-1)) - 1);
  const float s = fmaxf(__uint_as_float(amax[which]) / qmax, 1e-8f);
  if (which == 0){
    if (idx >= MPAD*NPAD) return;
    int m = idx / NPAD, n = idx - m*NPAD;
    float v = 0.f;
    if (m < Nn && n < Nn){
      float q = fminf(fmaxf(rintf(Wa[m*Nn + n] / s), -qmax), qmax);
      v = q * s;
    }
    Wq[idx] = f2bf(v);
  } else {
    const float* W = (which == 1) ? W1 : W2;
    ushort* Wo = (which == 1) ? W1q : W2q;
    float q = fminf(fmaxf(rintf(W[idx] / s), -qmax), qmax);
    Wo[idx] = f2bf(q * s);
  }
}

// ---------- stage a 128x32 bf16 tile into linear LDS [128][32] via global_load_lds ----------
__device__ __forceinline__ void stage_tile(const ushort* __restrict__ src, long ld, int k0,
                                           ushort* dst){
  const int tid = threadIdx.x;
  const long row = tid >> 2;
  const int  c8  = (tid & 3) * 8;
  GLD16(src + row*ld + k0 + c8,        dst + tid*8);          // rows 0..63
  GLD16(src + (row+64)*ld + k0 + c8,   dst + 2048 + tid*8);   // rows 64..127
}

// ---------- 128x128 bf16 MFMA tile core (m97 structure; verified in r2) ----------
// acc[i][j]: C[row from A-tile rows][col from B-tile rows].
// Thread's C mapping: row = wr*64+i*16+(lane>>4)*4+r (4 CONSECUTIVE), col = wc*64+j*16+(lane&15).
__device__ __forceinline__ void gemm_core_gl(const ushort* __restrict__ A, long ldA,
                                             const ushort* __restrict__ B, long ldB,
                                             int K, ushort* As, ushort* Bs, f32x4 acc[4][4]){
  const int tid  = threadIdx.x;
  const int lane = tid & 63;
  const int wr   = (tid >> 7) & 1;
  const int wc   = (tid >> 6) & 1;
  const int arow = lane & 15;
  const int koff = (lane >> 4) * 8;
  for (int k0 = 0; k0 < K; k0 += 32){
    __syncthreads();                 // protect LDS from previous iteration's readers
    stage_tile(A, ldA, k0, As);
    stage_tile(B, ldB, k0, Bs);
    __syncthreads();                 // drains vmcnt before ds_read
    bf16x8 ag[4], bg[4];
    #pragma unroll
    for (int i=0;i<4;i++){
      ag[i] = *(const bf16x8*)&As[(wr*64 + i*16 + arow)*32 + koff];
      bg[i] = *(const bf16x8*)&Bs[(wc*64 + i*16 + arow)*32 + koff];
    }
    #pragma unroll
    for (int i=0;i<4;i++)
      #pragma unroll
      for (int j=0;j<4;j++)
        acc[i][j] = MFMA16(ag[i], bg[j], acc[i][j]);
  }
}

// ---------- GEMM1 fused: norm1 + transpose + token-mix + layerscale/residual + norm2 ----------
// (r12 kernel, unchanged: swapped operands -> float4 epilogue)
__global__ __launch_bounds__(256, 2) void gemm1_k(const ushort* __restrict__ Wq,
    const float* __restrict__ x,
    const float* __restrict__ alpha1, const float* __restrict__ beta1,
    const float* __restrict__ b_attn, const float* __restrict__ gamma1,
    const float* __restrict__ alpha2, const float* __restrict__ beta2,
    float* __restrict__ x1, ushort* __restrict__ hn2){
  __shared__ ushort Xs[128*XLD];     // 59392 B
  __shared__ float  Sbuf[32*128];    // 16 KB f32 staging for the transpose
  const int tid = threadIdx.x;
  const int b = blockIdx.y, dt = blockIdx.x, d0 = dt*128;

  {
    const int dme = tid & 127;
    const float a1 = alpha1[d0 + dme], be1 = beta1[d0 + dme];
    for (int p = 0; p < 7; p++){
      __syncthreads();
      #pragma unroll
      for (int c = 0; c < 4; c++){
        int nn = p*32 + c*8 + (tid >> 5);
        int ncl = nn < Nn ? nn : Nn - 1;          // clamp (no OOB); zeroed at transpose
        GLD16(x + ((long)b*Nn + ncl)*Dd + d0 + (tid & 31)*4,
              (char*)Sbuf + c*4096 + tid*16);
      }
      __syncthreads();
      for (int g = tid >> 7; g < 4; g += 2){      // each thread: 2 groups of 8 n
        int n0 = g*8;
        ushort o[8];
        #pragma unroll
        for (int t = 0; t < 8; t++){
          int na = p*32 + n0 + t;
          float val = (na < Nn) ? fmaf(a1, Sbuf[(n0 + t)*128 + dme], be1) : 0.f;
          o[t] = f2bf(val);
        }
        *(int4*)&Xs[dme*XLD + p*32 + n0] = *(int4*)o;
      }
    }
  }
  __syncthreads();   // Xs complete; read-only from here (no more barriers)

  const int lane = tid & 63;
  const int wr = (tid >> 7) & 1, wc = (tid >> 6) & 1;
  const int arow = lane & 15, koff = (lane >> 4)*8;
  const int g = lane >> 4;
  for (int mt = 0; mt < 2; mt++){
    f32x4 acc[4][4] = {};   // acc[i=d-subtile][j=m-subtile]
    #pragma unroll
    for (int k7 = 0; k7 < 7; k7++){
      bf16x8 ag[4], bg[4];
      #pragma unroll
      for (int i=0;i<4;i++){
        int row = mt*128 + wr*64 + i*16 + arow;
        ag[i] = *(const bf16x8*)&Wq[row*NPAD + k7*32 + koff];        // L2-hot global
        bg[i] = *(const bf16x8*)&Xs[(wc*64 + i*16 + arow)*XLD + k7*32 + koff];
      }
      // SWAPPED: A-operand = Xs (d-rows), B-operand = Wq (m-cols) -> D[d][m]
      #pragma unroll
      for (int i=0;i<4;i++)
        #pragma unroll
        for (int j=0;j<4;j++)
          acc[i][j] = MFMA16(bg[i], ag[j], acc[i][j]);
    }
    #pragma unroll
    for (int i=0;i<4;i++){
      const int d = d0 + wc*64 + i*16 + g*4;
      const float4 g1 = *(const float4*)&gamma1[d];
      const float4 a2 = *(const float4*)&alpha2[d];
      const float4 b2v = *(const float4*)&beta2[d];
      #pragma unroll
      for (int j=0;j<4;j++){
        const int m = mt*128 + wr*64 + j*16 + arow;
        if (m < Nn){
          const long base = ((long)b*Nn + m)*Dd + d;
          const float4 xv = *(const float4*)&x[base];     // L2-warm (prologue loaded it)
          const float ba = b_attn[m];
          float4 o;
          o.x = fmaf(g1.x, acc[i][j][0] + ba, xv.x);
          o.y = fmaf(g1.y, acc[i][j][1] + ba, xv.y);
          o.z = fmaf(g1.z, acc[i][j][2] + ba, xv.z);
          o.w = fmaf(g1.w, acc[i][j][3] + ba, xv.w);
          *(float4*)&x1[base] = o;
          ushort h4[4];
          h4[0] = f2bf(fmaf(a2.x, o.x, b2v.x));
          h4[1] = f2bf(fmaf(a2.y, o.y, b2v.y));
          h4[2] = f2bf(fmaf(a2.z, o.z, b2v.z));
          h4[3] = f2bf(fmaf(a2.w, o.w, b2v.w));
          *(int2*)&hn2[base] = *(int2*)h4;
        }
      }
    }
  }
}

// ---------- GEMM2: h2 = bf16(gelu(hn2 @ W1q^T + b1)), D[h][tok] for int2 epilogue ----------
__global__ __launch_bounds__(256) void gemm2_k(const ushort* __restrict__ hn2,
    const ushort* __restrict__ W1q, const float* __restrict__ b1,
    ushort* __restrict__ h2, int t0c){
  __shared__ ushort As[4096];
  __shared__ ushort Bs[4096];
  const int ht = blockIdx.x, tt = blockIdx.y;   // x fastest: 12 ht-blocks share B-tile
  const long t0 = (long)t0c + tt*128;
  f32x4 acc[4][4] = {};
  // A = W1 rows (h, output rows), B = hn2 rows (tok, output cols), K = 384
  gemm_core_gl(W1q + (long)ht*128*Dd, Dd, hn2 + t0*Dd, Dd, Dd, As, Bs, acc);
  const int lane = threadIdx.x & 63;
  const int wr = (threadIdx.x >> 7) & 1, wc = (threadIdx.x >> 6) & 1;
  const int arow = lane & 15, g = lane >> 4;
  #pragma unroll
  for (int i=0;i<4;i++){
    const int h0 = ht*128 + wr*64 + i*16 + g*4;
    const float4 b1v = *(const float4*)&b1[h0];
    #pragma unroll
    for (int j=0;j<4;j++){
      const long tok = t0 + wc*64 + j*16 + arow;
      ushort h4[4];
      #pragma unroll
      for (int r=0;r<4;r++){
        float v = acc[i][j][r] + ((const float*)&b1v)[r];
        // jax.nn.gelu approximate: v * sigmoid(1.5957691*(v + 0.044715 v^3))
        float u = 0.7978845608028654f * v * fmaf(0.044715f, v*v, 1.f);
        float gl = v / (1.f + __expf(-2.f*u));
        h4[r] = f2bf(gl);
      }
      *(int2*)&h2[tok*Hh + h0] = *(int2*)h4;
    }
  }
}

// ---------- GEMM3: out += gamma2*(h2 @ W2q^T + b2), D[d][tok] for float4 RMW ----------
__global__ __launch_bounds__(256) void gemm3_k(const ushort* __restrict__ h2,
    const ushort* __restrict__ W2q, const float* __restrict__ b2,
    const float* __restrict__ gamma2, float* __restrict__ out, int t0c){
  __shared__ ushort As[4096];
  __shared__ ushort Bs[4096];
  const int dt = blockIdx.x, tt = blockIdx.y;   // x fastest: 3 dt-blocks share B-tile
  const long t0 = (long)t0c + tt*128;
  f32x4 acc[4][4] = {};
  // A = W2 rows (d, output rows), B = h2 rows (tok, output cols), K = 1536
  gemm_core_gl(W2q + (long)dt*128*Hh, Hh, h2 + t0*Hh, Hh, Hh, As, Bs, acc);
  const int lane = threadIdx.x & 63;
  const int wr = (threadIdx.x >> 7) & 1, wc = (threadIdx.x >> 6) & 1;
  const int arow = lane & 15, g = lane >> 4;
  #pragma unroll
  for (int i=0;i<4;i++){
    const int d = dt*128 + wr*64 + i*16 + g*4;
    const float4 g2 = *(const float4*)&gamma2[d];
    const float4 bv = *(const float4*)&b2[d];
    #pragma unroll
    for (int j=0;j<4;j++){
      const long tok = t0 + wc*64 + j*16 + arow;
      const long base = tok*Dd + d;
      float4 o = *(const float4*)&out[base];    // x1 residual staged in out
      o.x = fmaf(g2.x, acc[i][j][0] + bv.x, o.x);
      o.y = fmaf(g2.y, acc[i][j][1] + bv.y, o.y);
      o.z = fmaf(g2.z, acc[i][j][2] + bv.z, o.z);
      o.w = fmaf(g2.w, acc[i][j][3] + bv.w, o.w);
      *(float4*)&out[base] = o;
    }
  }
}

extern "C" void kernel_launch(void* const* d_in, const int* in_sizes, int n_in,
                              void* d_out, int out_size, void* d_ws, size_t ws_size,
                              hipStream_t stream){
  const float* x      = (const float*)d_in[0];
  const float* alpha1 = (const float*)d_in[1];
  const float* beta1  = (const float*)d_in[2];
  const float* W_attn = (const float*)d_in[3];
  const float* b_attn = (const float*)d_in[4];
  const float* gamma1 = (const float*)d_in[5];
  const float* alpha2 = (const float*)d_in[6];
  const float* beta2  = (const float*)d_in[7];
  const float* W1     = (const float*)d_in[8];
  const float* b1     = (const float*)d_in[9];
  const float* W2     = (const float*)d_in[10];
  const float* b2     = (const float*)d_in[11];
  const float* gamma2 = (const float*)d_in[12];
  const int*   bits   = (const int*)d_in[13];

  // ws layout (256B aligned)
  char* ws = (char*)d_ws;
  unsigned* amax = (unsigned*)ws;                    // [3]
  ushort* Wq   = (ushort*)(ws + 256);                // [256][224] bf16
  ushort* W1q  = (ushort*)(ws + 114944);             // [1536][384]
  ushort* W2q  = (ushort*)(ws + 1294592);            // [384][1536]
  ushort* hn2  = (ushort*)(ws + 2474240);            // [50176][384]
  ushort* h2   = (ushort*)(ws + 41009408);           // [50176][1536] (154 MB; ws >= 195 MB per r2)
  float*  x1   = (float*)d_out;                      // residual staged in d_out

  hipMemsetAsync(amax, 0, 256, stream);
  absmax3_k<<<dim3(128, 3), 256, 0, stream>>>(W_attn, W1, W2, amax);
  quant_all_k<<<dim3((Hh*Dd)/256, 3), 256, 0, stream>>>(W_attn, W1, W2, amax, bits,
                                                        Wq, W1q, W2q);
  gemm1_k<<<dim3(3, Bb), 256, 0, stream>>>(Wq, x, alpha1, beta1, b_attn, gamma1,
                                           alpha2, beta2, x1, hn2);
  for (int c = 0; c < 2; c++){
    gemm2_k<<<dim3(Hh/128, TC/128), 256, 0, stream>>>(hn2, W1q, b1, h2, c*TC);
    gemm3_k<<<dim3(Dd/128, TC/128), 256, 0, stream>>>(h2, W2q, b2, gamma2,
                                                      (float*)d_out, c*TC);
  }
}

// Round 14
// 321.615 us; speedup vs baseline: 1.2668x; 1.2668x over previous
//
#include <hip/hip_runtime.h>
#include <hip/hip_bf16.h>
#include <stdint.h>

// Problem dims (fixed by harness)
#define Bb 256
#define Nn 196
#define Dd 384
#define Hh 1536
#define NPAD 224      // patch-dim K padded to 7*32 for MFMA
#define MPAD 256      // Wq row pad to 2*128 tiles
#define TTOT (Bb*Nn)  // 50176 tokens
#define XLD 232       // padded LDS stride for Xs (224+8): breaks bank aliasing
#define TK 128        // tokens per mlp block (50176/128 = 392 blocks exactly)
#define HS 128        // hidden slice per pass (1536/128 = 12 passes)

typedef __attribute__((ext_vector_type(8))) __bf16 bf16x8;
typedef __attribute__((ext_vector_type(4))) float f32x4;

// async global->LDS, 16B per lane. LDS dest must be wave-uniform base + lane*16.
#define GLD16(gp, lp) __builtin_amdgcn_global_load_lds( \
    (const __attribute__((address_space(1))) void*)(gp), \
    (__attribute__((address_space(3))) void*)(lp), 16, 0, 0)

#define MFMA16(a, b, c) __builtin_amdgcn_mfma_f32_16x16x32_bf16((a), (b), (c), 0, 0, 0)

__device__ __forceinline__ ushort f2bf(float f){
  union { float f; unsigned u; } v; v.f = f;
  unsigned r = v.u + 0x7FFFu + ((v.u >> 16) & 1u);   // RNE f32->bf16
  return (ushort)(r >> 16);
}

// ---------- absmax over the three weight tensors in one launch (y = tensor id) ----------
__global__ void absmax3_k(const float* __restrict__ wa, const float* __restrict__ w1,
                          const float* __restrict__ w2, unsigned* __restrict__ out){
  int which = blockIdx.y;
  const float* w = which == 0 ? wa : (which == 1 ? w1 : w2);
  int n = which == 0 ? Nn*Nn : Hh*Dd;
  float m = 0.f;
  for (int i = blockIdx.x*blockDim.x + threadIdx.x; i < n; i += gridDim.x*blockDim.x)
    m = fmaxf(m, fabsf(w[i]));
  #pragma unroll
  for (int o = 32; o >= 1; o >>= 1) m = fmaxf(m, __shfl_xor(m, o));
  __shared__ float sm[4];
  if ((threadIdx.x & 63) == 0) sm[threadIdx.x >> 6] = m;
  __syncthreads();
  if (threadIdx.x == 0){
    float mm = fmaxf(fmaxf(sm[0], sm[1]), fmaxf(sm[2], sm[3]));
    atomicMax(out + which, __float_as_uint(mm));   // floats >=0: uint order == float order
  }
}

// ---------- fake-quant all three weights in one launch (y = tensor id) ----------
__global__ void quant_all_k(const float* __restrict__ Wa, const float* __restrict__ W1,
                            const float* __restrict__ W2, const unsigned* __restrict__ amax,
                            const int* __restrict__ bitsp,
                            ushort* __restrict__ Wq, ushort* __restrict__ W1q,
                            ushort* __restrict__ W2q){
  const int which = blockIdx.y;
  const int idx = blockIdx.x*256 + threadIdx.x;
  const float qmax = (float)((1 << (bitsp[0]-1)) - 1);
  const float s = fmaxf(__uint_as_float(amax[which]) / qmax, 1e-8f);
  if (which == 0){
    if (idx >= MPAD*NPAD) return;
    int m = idx / NPAD, n = idx - m*NPAD;
    float v = 0.f;
    if (m < Nn && n < Nn){
      float q = fminf(fmaxf(rintf(Wa[m*Nn + n] / s), -qmax), qmax);
      v = q * s;
    }
    Wq[idx] = f2bf(v);
  } else {
    const float* W = (which == 1) ? W1 : W2;
    ushort* Wo = (which == 1) ? W1q : W2q;
    float q = fminf(fmaxf(rintf(W[idx] / s), -qmax), qmax);
    Wo[idx] = f2bf(q * s);
  }
}

// ---------- GEMM1 fused: norm1 + TRANSPOSE-ON-LOAD + token-mix + residual + norm2 ----------
// v2 prologue: each thread owns one d-column; reads x[b][n][d] as coalesced-in-d scalar
// loads (for fixed n, 128 consecutive-d threads = 512B segments), norms in reg, writes Xs
// in final [d][n] layout. NO Sbuf, NO transpose pass, ONE barrier before the main loop.
// Main loop: A-frags from global Wq (L2-resident), B = persistent Xs; swapped operands
// -> D[d][m], float4 epilogue (r12-verified).
__global__ __launch_bounds__(256, 2) void gemm1_k(const ushort* __restrict__ Wq,
    const float* __restrict__ x,
    const float* __restrict__ alpha1, const float* __restrict__ beta1,
    const float* __restrict__ b_attn, const float* __restrict__ gamma1,
    const float* __restrict__ alpha2, const float* __restrict__ beta2,
    float* __restrict__ x1, ushort* __restrict__ hn2){
  __shared__ ushort Xs[128*XLD];     // 59392 B (only LDS in kernel -> 2 blocks/CU)
  const int tid = threadIdx.x;
  const int b = blockIdx.y, dt = blockIdx.x, d0 = dt*128;

  // ---- build Xs[d][n]: thread (dme, ng) covers n-octets (p*2+ng)*8, p=0..13 (n<224) ----
  {
    const int dme = tid & 127;
    const int ng  = tid >> 7;
    const float a1 = alpha1[d0 + dme], be1 = beta1[d0 + dme];
    const float* xcol = x + (long)b*Nn*Dd + d0 + dme;
    #pragma unroll
    for (int p = 0; p < 14; p++){
      const int n0 = (p*2 + ng)*8;
      ushort o[8];
      #pragma unroll
      for (int t = 0; t < 8; t++){
        const int n = n0 + t;
        float v = 0.f;
        if (n < Nn) v = fmaf(a1, xcol[(long)n*Dd], be1);
        o[t] = f2bf(v);
      }
      *(int4*)&Xs[dme*XLD + n0] = *(int4*)o;
    }
  }
  __syncthreads();   // Xs complete; read-only from here (no more barriers)

  const int lane = tid & 63;
  const int wr = (tid >> 7) & 1, wc = (tid >> 6) & 1;
  const int arow = lane & 15, koff = (lane >> 4)*8;
  const int g = lane >> 4;
  for (int mt = 0; mt < 2; mt++){
    f32x4 acc[4][4] = {};   // acc[i=d-subtile][j=m-subtile]
    #pragma unroll
    for (int k7 = 0; k7 < 7; k7++){
      bf16x8 ag[4], bg[4];
      #pragma unroll
      for (int i=0;i<4;i++){
        int row = mt*128 + wr*64 + i*16 + arow;
        ag[i] = *(const bf16x8*)&Wq[row*NPAD + k7*32 + koff];        // L2-hot global
        bg[i] = *(const bf16x8*)&Xs[(wc*64 + i*16 + arow)*XLD + k7*32 + koff];
      }
      // SWAPPED: A-operand = Xs (d-rows), B-operand = Wq (m-cols) -> D[d][m]
      #pragma unroll
      for (int i=0;i<4;i++)
        #pragma unroll
        for (int j=0;j<4;j++)
          acc[i][j] = MFMA16(bg[i], ag[j], acc[i][j]);
    }
    // ---- vectorized epilogue: thread owns d..d+3 (consecutive) x m ----
    #pragma unroll
    for (int i=0;i<4;i++){
      const int d = d0 + wc*64 + i*16 + g*4;
      const float4 g1 = *(const float4*)&gamma1[d];
      const float4 a2 = *(const float4*)&alpha2[d];
      const float4 b2v = *(const float4*)&beta2[d];
      #pragma unroll
      for (int j=0;j<4;j++){
        const int m = mt*128 + wr*64 + j*16 + arow;
        if (m < Nn){
          const long base = ((long)b*Nn + m)*Dd + d;
          const float4 xv = *(const float4*)&x[base];     // L2-warm (prologue streamed it)
          const float ba = b_attn[m];
          float4 o;
          o.x = fmaf(g1.x, acc[i][j][0] + ba, xv.x);
          o.y = fmaf(g1.y, acc[i][j][1] + ba, xv.y);
          o.z = fmaf(g1.z, acc[i][j][2] + ba, xv.z);
          o.w = fmaf(g1.w, acc[i][j][3] + ba, xv.w);
          *(float4*)&x1[base] = o;
          ushort h4[4];
          h4[0] = f2bf(fmaf(a2.x, o.x, b2v.x));
          h4[1] = f2bf(fmaf(a2.y, o.y, b2v.y));
          h4[2] = f2bf(fmaf(a2.z, o.z, b2v.z));
          h4[3] = f2bf(fmaf(a2.w, o.w, b2v.w));
          *(int2*)&hn2[base] = *(int2*)h4;
        }
      }
    }
  }
}

// ================== fused MLP: round-8 kernel VERBATIM (best measured: 251 us) ==================
// TK=128, 512 thr, 2-slot 2-phase; stage next unit BEFORE compute; one barrier per phase.

// A-unit (32KB): As[128 tok][64 k] at slot+0, W1s[128 h][64 k] at slot+8192 (ushorts).
__device__ __forceinline__ void stage_A(const ushort* __restrict__ hn2t,
                                        const ushort* __restrict__ W1q, int hs, int ka,
                                        ushort* slot){
  const int tid = threadIdx.x;
  const int r  = tid >> 3;                       // 0..63
  const int us = ((tid & 7) ^ (r & 7)) * 8;      // swizzled source col (ushorts)
  const int k0 = ka*64;
  const ushort* w1 = W1q + (long)hs*HS*Dd + k0;
  GLD16(hn2t + (long)r*Dd + k0 + us,        slot + tid*8);           // As rows 0..63
  GLD16(hn2t + (long)(r+64)*Dd + k0 + us,   slot + 4096 + tid*8);    // As rows 64..127
  GLD16(w1 + (long)r*Dd + us,               slot + 8192 + tid*8);    // W1 rows 0..63
  GLD16(w1 + (long)(r+64)*Dd + us,          slot + 12288 + tid*8);   // W1 rows 64..127
}

// B-unit (24KB): W2s[384 d][32 k]. Source col-unit XOR-swizzled by (row>>1)&3.
__device__ __forceinline__ void stage_B(const ushort* __restrict__ W2q, int hs, int kb,
                                        ushort* slot){
  const int tid = threadIdx.x;
  const int r  = tid >> 2;                       // 0..127
  const int us = ((tid & 3) ^ ((r >> 1) & 3)) * 8;
  const ushort* w2 = W2q + hs*HS + kb*32;
  GLD16(w2 + (long)r*Hh + us,          slot + tid*8);          // rows 0..127
  GLD16(w2 + (long)(r+128)*Hh + us,    slot + 4096 + tid*8);   // rows 128..255
  GLD16(w2 + (long)(r+256)*Hh + us,    slot + 8192 + tid*8);   // rows 256..383
}

__global__ __launch_bounds__(512, 2) void mlp_k(const ushort* __restrict__ hn2,
    const ushort* __restrict__ W1q, const ushort* __restrict__ W2q,
    const float* __restrict__ b1, const float* __restrict__ b2,
    const float* __restrict__ gamma2, float* __restrict__ out){
  __shared__ ushort SH[49152];       // 96 KB: 2 slots of 32 KB + Ps 32 KB
  ushort* const buf0 = SH;
  ushort* const buf1 = SH + 16384;
  ushort* const Ps   = SH + 32768;   // [128][128] bf16, XOR-swizzled rows

  const int tid  = threadIdx.x;
  const int lane = tid & 63;
  const int wv   = tid >> 6;           // 0..7
  const int wt   = wv >> 2;            // token half (0/1)
  const int wh   = wv & 3;             // h quarter (GEMM-a) / d quarter (GEMM-b)
  const int arow = lane & 15;
  const int a7   = arow & 7;
  const int g    = lane >> 4;          // 0..3
  const long t0  = (long)blockIdx.x * TK;
  const ushort* hn2t = hn2 + t0*Dd;

  stage_A(hn2t, W1q, 0, 0, buf0);
  __syncthreads();

  f32x4 oacc[4][6] = {};
  int cur = 0;

  for (int hs = 0; hs < 12; ++hs){
    f32x4 pacc[4][2] = {};
    // ---- GEMM-a: P[128 tok][128 h] = hn2_tile @ W1_slice^T, 6 phases of BK=64 ----
    #pragma unroll
    for (int ka = 0; ka < 6; ++ka){
      ushort* nslot = cur ? buf0 : buf1;
      if (ka < 5) stage_A(hn2t, W1q, hs, ka+1, nslot);
      else        stage_B(W2q, hs, 0, nslot);          // B0 flies over phase a5 + gelu
      const ushort* Asl = cur ? buf1 : buf0;
      const ushort* W1l = Asl + 8192;
      bf16x8 ag[4][2], bg[2][2];
      #pragma unroll
      for (int ks=0; ks<2; ks++){
        const int cu8 = ((ks*4 + g) ^ a7) * 8;
        #pragma unroll
        for (int i=0;i<4;i++)
          ag[i][ks] = *(const bf16x8*)&Asl[(wt*64 + i*16 + arow)*64 + cu8];
        #pragma unroll
        for (int j=0;j<2;j++)
          bg[j][ks] = *(const bf16x8*)&W1l[(wh*32 + j*16 + arow)*64 + cu8];
      }
      __builtin_amdgcn_s_setprio(1);
      #pragma unroll
      for (int ks=0;ks<2;ks++)
        #pragma unroll
        for (int i=0;i<4;i++)
          #pragma unroll
          for (int j=0;j<2;j++)
            pacc[i][j] = MFMA16(ag[i][ks], bg[j][ks], pacc[i][j]);
      __builtin_amdgcn_s_setprio(0);
      __syncthreads();
      cur ^= 1;
    }
    // ---- bias + gelu -> Ps (swizzled: idx = row*HS + (h ^ ((row&7)<<3))) ----
    #pragma unroll
    for (int j=0;j<2;j++){
      int hcol = wh*32 + j*16 + arow;
      float b1v = b1[hs*HS + hcol];
      #pragma unroll
      for (int i=0;i<4;i++){
        #pragma unroll
        for (int r=0;r<4;r++){
          int row = wt*64 + i*16 + g*4 + r;
          float v = pacc[i][j][r] + b1v;
          // jax.nn.gelu approximate: v * sigmoid(1.5957691*(v + 0.044715 v^3))
          float u = 0.7978845608028654f * v * fmaf(0.044715f, v*v, 1.f);
          float gl = v / (1.f + __expf(-2.f*u));
          Ps[row*HS + (hcol ^ ((row & 7) << 3))] = f2bf(gl);
        }
      }
    }
    __syncthreads();   // Ps visible; also drains B0's DMA (flew during a5+gelu)
    // ---- GEMM-b: oacc[128 tok][384 d] += P @ W2_slice^T, 4 phases of BK=32 ----
    #pragma unroll
    for (int kb = 0; kb < 4; ++kb){
      ushort* nslot = cur ? buf0 : buf1;
      if (kb < 3) stage_B(W2q, hs, kb+1, nslot);
      else        stage_A(hn2t, W1q, (hs+1) % 12, 0, nslot);   // next-hs A0 (hs=11: dummy)
      const ushort* W2l = cur ? buf1 : buf0;
      bf16x8 pa[4], bgb[6];
      #pragma unroll
      for (int i=0;i<4;i++){
        int row = wt*64 + i*16 + arow;
        pa[i] = *(const bf16x8*)&Ps[row*HS + ((kb*32 + g*8) ^ (a7 << 3))];
      }
      const int u8 = (g ^ ((arow >> 1) & 3)) * 8;
      #pragma unroll
      for (int j=0;j<6;j++)
        bgb[j] = *(const bf16x8*)&W2l[(wh*96 + j*16 + arow)*32 + u8];
      __builtin_amdgcn_s_setprio(1);
      #pragma unroll
      for (int i=0;i<4;i++)
        #pragma unroll
        for (int j=0;j<6;j++)
          oacc[i][j] = MFMA16(pa[i], bgb[j], oacc[i][j]);
      __builtin_amdgcn_s_setprio(0);
      __syncthreads();
      cur ^= 1;
    }
  }

  // ---- epilogue: out = gamma2*(oacc + b2) + x1 (x1 staged in out) ----
  #pragma unroll
  for (int i=0;i<4;i++){
    #pragma unroll
    for (int j=0;j<6;j++){
      int d = wh*96 + j*16 + arow;
      float g2 = gamma2[d], b2v = b2[d];
      #pragma unroll
      for (int r=0;r<4;r++){
        long t = t0 + wt*64 + i*16 + g*4 + r;
        long idx = t*Dd + d;
        out[idx] = fmaf(g2, oacc[i][j][r] + b2v, out[idx]);
      }
    }
  }
}

extern "C" void kernel_launch(void* const* d_in, const int* in_sizes, int n_in,
                              void* d_out, int out_size, void* d_ws, size_t ws_size,
                              hipStream_t stream){
  const float* x      = (const float*)d_in[0];
  const float* alpha1 = (const float*)d_in[1];
  const float* beta1  = (const float*)d_in[2];
  const float* W_attn = (const float*)d_in[3];
  const float* b_attn = (const float*)d_in[4];
  const float* gamma1 = (const float*)d_in[5];
  const float* alpha2 = (const float*)d_in[6];
  const float* beta2  = (const float*)d_in[7];
  const float* W1     = (const float*)d_in[8];
  const float* b1     = (const float*)d_in[9];
  const float* W2     = (const float*)d_in[10];
  const float* b2     = (const float*)d_in[11];
  const float* gamma2 = (const float*)d_in[12];
  const int*   bits   = (const int*)d_in[13];

  // ws layout (256B aligned)
  char* ws = (char*)d_ws;
  unsigned* amax = (unsigned*)ws;                    // [3]
  ushort* Wq   = (ushort*)(ws + 256);                // [256][224] bf16
  ushort* W1q  = (ushort*)(ws + 114944);             // [1536][384]
  ushort* W2q  = (ushort*)(ws + 1294592);            // [384][1536]
  ushort* hn2  = (ushort*)(ws + 2474240);            // [50176][384]
  float*  x1   = (float*)d_out;                      // residual staged in d_out

  hipMemsetAsync(amax, 0, 256, stream);
  absmax3_k<<<dim3(128, 3), 256, 0, stream>>>(W_attn, W1, W2, amax);
  quant_all_k<<<dim3((Hh*Dd)/256, 3), 256, 0, stream>>>(W_attn, W1, W2, amax, bits,
                                                        Wq, W1q, W2q);
  gemm1_k<<<dim3(3, Bb), 256, 0, stream>>>(Wq, x, alpha1, beta1, b_attn, gamma1,
                                           alpha2, beta2, x1, hn2);
  mlp_k<<<TTOT/TK, 512, 0, stream>>>(hn2, W1q, W2q, b1, b2, gamma2, (float*)d_out);
}